// Round 4
// baseline (1764.186 us; speedup 1.0000x reference)
//
#include <hip/hip_runtime.h>

// Elman RNN, T=512 B=64 I=256 H=512, fp32 in/out. Single fused dispatch:
//  - blocks 4..255 (proj): xw[t,g-slab] = W_ih x + b_ih + b_hh via bf16 MFMA
//    (A=W_ih bf16-hi in regs, B=x hi/lo in LDS), written to d_out in MFMA
//    C-fragment order; per-slab flag released via __threadfence+atomicAdd.
//  - blocks 0..3 (scan): persistent, one per 16-batch group. W_hh int8 in
//    128 regs/lane, h int8 double-buffered in LDS (stride 528). Per step:
//    coherent (agent-scope) xw loads issued early + consumed in epilogue,
//    flag[t+1] checked early/confirmed pre-barrier, 32 i8 MFMAs, magic-number
//    quant (fma + v_perm pack), one barrier. h_seq stores deferred one step
//    (slab t reads fully drained at step-t barrier before t+1's overwrite).

#define T_LEN 512
#define NBATCH 64
#define ISZ 256
#define HSZ 512
#define NPROJ 252

typedef __attribute__((ext_vector_type(8))) short short8;
typedef __attribute__((ext_vector_type(4))) int int4v;
typedef __attribute__((ext_vector_type(4))) float f32x4;

__device__ __forceinline__ unsigned short f2bf(float f) {
  unsigned u = __float_as_uint(f);
  u += 0x7fffu + ((u >> 16) & 1u);   // RNE
  return (unsigned short)(u >> 16);
}
__device__ __forceinline__ float bf2f(unsigned short h) {
  return __uint_as_float(((unsigned)h) << 16);
}

__global__ void init_flags(int* f) { f[blockIdx.x * 512 + threadIdx.x] = 0; }

__global__ __launch_bounds__(512, 2) void rnn_fused(
    const float* __restrict__ x, const float* __restrict__ h0,
    const float* __restrict__ Wih, const float* __restrict__ Whh,
    const float* __restrict__ bih, const float* __restrict__ bhh,
    float* __restrict__ out, int* __restrict__ flags) {
  __shared__ __align__(16) char smem[16896];

  const int tid = threadIdx.x;
  const int w  = tid >> 6;    // wave 0..7
  const int L  = tid & 63;
  const int lr = L & 15;
  const int lg = L >> 4;

  if (blockIdx.x >= 4) {
    // ================= proj role: full (t,g)-slabs, flag per slab ==========
    const int pb = blockIdx.x - 4;           // 0..251
    short (*xhi)[264] = (short(*)[264])smem;
    short (*xlo)[264] = (short(*)[264])(smem + 8448);

    // A = W_ih bf16 (hi only): 4 m-tiles x 8 kt -> 128 regs/lane
    short8 Ah[4][8];
    f32x4 bias[4];
#pragma unroll
    for (int m = 0; m < 4; ++m) {
      const int mt = 4 * w + m;
      const int j = mt * 16 + lr;
#pragma unroll
      for (int kt = 0; kt < 8; ++kt) {
        const float* p = Wih + (size_t)j * ISZ + kt * 32 + lg * 8;
        const f32x4 v0 = *(const f32x4*)p;
        const f32x4 v1 = *(const f32x4*)(p + 4);
        short8 a;
#pragma unroll
        for (int i = 0; i < 4; ++i) {
          a[i]     = (short)f2bf(v0[i]);
          a[i + 4] = (short)f2bf(v1[i]);
        }
        Ah[m][kt] = a;
      }
      f32x4 b1 = *(const f32x4*)(bih + mt * 16 + lg * 4);
      f32x4 b2 = *(const f32x4*)(bhh + mt * 16 + lg * 4);
      bias[m] = b1 + b2;
    }

    for (int tau = pb; tau < T_LEN * 4; tau += NPROJ) {
      const int t = tau >> 2;
      const int g = tau & 3;

      __syncthreads();   // previous iteration's LDS readers done
      {
        const int f   = tid * 8;
        const int row = f >> 8;
        const int i0  = f & 255;
        const float* p = x + ((size_t)(t * NBATCH + g * 16 + row) * ISZ + i0);
        const f32x4 v0 = *(const f32x4*)p;
        const f32x4 v1 = *(const f32x4*)(p + 4);
        short8 hi, lo;
#pragma unroll
        for (int i = 0; i < 4; ++i) {
          unsigned short h1 = f2bf(v0[i]);
          hi[i] = (short)h1; lo[i] = (short)f2bf(v0[i] - bf2f(h1));
          unsigned short h2 = f2bf(v1[i]);
          hi[i + 4] = (short)h2; lo[i + 4] = (short)f2bf(v1[i] - bf2f(h2));
        }
        *(short8*)(&xhi[row][i0]) = hi;
        *(short8*)(&xlo[row][i0]) = lo;
      }
      __syncthreads();

      f32x4 acc[4];
#pragma unroll
      for (int m = 0; m < 4; ++m) acc[m] = f32x4{0.f, 0.f, 0.f, 0.f};
#pragma unroll
      for (int kt = 0; kt < 8; ++kt) {
        const int koff = kt * 32 + lg * 8;
        short8 bh = *(const short8*)(&xhi[lr][koff]);
        short8 bl = *(const short8*)(&xlo[lr][koff]);
#pragma unroll
        for (int m = 0; m < 4; ++m) {
          acc[m] = __builtin_amdgcn_mfma_f32_16x16x32_bf16(Ah[m][kt], bh, acc[m], 0, 0, 0);
          acc[m] = __builtin_amdgcn_mfma_f32_16x16x32_bf16(Ah[m][kt], bl, acc[m], 0, 0, 0);
        }
      }
#pragma unroll
      for (int m = 0; m < 4; ++m) {
        f32x4 r = acc[m] + bias[m];
        *(f32x4*)(out + (size_t)((((t * 4 + g) * 32 + 4 * w + m) * 64) + L) * 4) = r;
      }
      __syncthreads();   // all stores issued+drained (barrier waits vmcnt(0))
      if (tid == 0) {
        __threadfence();                 // release: L2 -> device-visible
        atomicAdd(&flags[tau], 1);
      }
    }
    return;
  }

  // ================== scan role: blocks 0..3, one per batch group ==========
  const int g = blockIdx.x;
  char* hb = smem;   // layout: (buf*16 + row)*528 + col  (col = k, 1B/elem)

  const float QS  = 127.0f * 22.627416997969522f;                 // 127*sqrt(512)
  const float DEQ = (float)(1.0 / (127.0 * 127.0 * 22.627416997969522));

  // W_hh int8 A-frags: 4 m-tiles x 8 kt x int4v = 128 regs/lane
  int4v A[4][8];
#pragma unroll
  for (int m = 0; m < 4; ++m) {
    const int j = (4 * w + m) * 16 + lr;
#pragma unroll
    for (int kt = 0; kt < 8; ++kt) {
      const float* p = Whh + (size_t)j * HSZ + kt * 64 + lg * 16;
      int dw[4];
#pragma unroll
      for (int d = 0; d < 4; ++d) {
        f32x4 v = *(const f32x4*)(p + d * 4);
        int pk = 0;
#pragma unroll
        for (int i = 0; i < 4; ++i) {
          float q = __builtin_rintf(fminf(fmaxf(v[i] * QS, -127.f), 127.f));
          pk |= ((int)q & 255) << (8 * i);
        }
        dw[d] = pk;
      }
      A[m][kt] = int4v{dw[0], dw[1], dw[2], dw[3]};
    }
  }

  // stage h0 (int8) into buffer 0
  {
    const int row = tid >> 5;
    const int k0  = (tid & 31) * 16;
    const float* p = h0 + ((size_t)(g * 16 + row) * HSZ + k0);
    int dw[4];
#pragma unroll
    for (int c = 0; c < 4; ++c) {
      f32x4 v = *(const f32x4*)(p + c * 4);
      int pk = 0;
#pragma unroll
      for (int i = 0; i < 4; ++i) {
        float q = __builtin_rintf(fminf(fmaxf(v[i] * 127.f, -127.f), 127.f));
        pk |= ((int)q & 255) << (8 * i);
      }
      dw[c] = pk;
    }
    *(int4v*)(hb + row * 528 + k0) = int4v{dw[0], dw[1], dw[2], dw[3]};
  }

  // wait for slab t=0
  if (tid == 0) {
    while (__hip_atomic_load(&flags[g], __ATOMIC_ACQUIRE, __HIP_MEMORY_SCOPE_AGENT) == 0)
      __builtin_amdgcn_s_sleep(2);
  }
  __syncthreads();

  const int j0 = 4 * w * 16 + lg * 4;                  // m=0 column base (floats)
  const char* xwp = (const char*)out + ((size_t)(g * 32 + 4 * w) * 64 + L) * 16;
  float* hsp = out + (size_t)(g * 16 + lr) * HSZ + j0; // slab-0 store base
  const int ldsr = lr * 528 + lg * 16;                 // ds_read base (+buf*8448+kt*64)
  const int ldsw = lr * 528 + j0;                      // ds_write base (+buf*8448+m*16)

  f32x4 pend[4];

  for (int t = 0; t < T_LEN; ++t) {
    const int cur = t & 1, nxt = cur ^ 1;

    // xw[t] coherent loads — issued now, consumed in epilogue (latency hidden)
    f32x4 xw[4];
#pragma unroll
    for (int m = 0; m < 4; ++m)
#pragma unroll
      for (int r = 0; r < 4; ++r)
        xw[m][r] = __hip_atomic_load((const float*)(xwp + m * 1024 + r * 4),
                                     __ATOMIC_RELAXED, __HIP_MEMORY_SCOPE_AGENT);

    // early flag check for slab t+1 (consumed pre-barrier)
    int tf = (t < T_LEN - 1) ? t + 1 : t;
    int fv = 1;
    if (tid == 0)
      fv = __hip_atomic_load(&flags[tf * 4 + g], __ATOMIC_RELAXED, __HIP_MEMORY_SCOPE_AGENT);

    // deferred h_seq store for slab t-1 (its readers drained at t-1's barrier)
    if (t > 0) {
#pragma unroll
      for (int m = 0; m < 4; ++m) *(f32x4*)(hsp + m * 16) = pend[m];
      hsp += NBATCH * HSZ;
    }

    // 32 i8 MFMAs: one b128 B-read feeds 4 m-chains
    int4v acc[4];
#pragma unroll
    for (int m = 0; m < 4; ++m) acc[m] = int4v{0, 0, 0, 0};
#pragma unroll
    for (int kt = 0; kt < 8; ++kt) {
      int4v B = *(const int4v*)(hb + cur * 8448 + ldsr + kt * 64);
#pragma unroll
      for (int m = 0; m < 4; ++m)
        acc[m] = __builtin_amdgcn_mfma_i32_16x16x64_i8(A[m][kt], B, acc[m], 0, 0, 0);
    }

    // epilogue: dequant + tanh + magic-number quant + v_perm pack
#pragma unroll
    for (int m = 0; m < 4; ++m) {
      unsigned qi[4];
      f32x4 h;
#pragma unroll
      for (int r = 0; r < 4; ++r) {
        float y  = fmaf((float)acc[m][r], DEQ, xw[m][r]);
        float e  = __builtin_amdgcn_exp2f(y * 2.8853900817779268f);  // e^{2y}
        float rc = __builtin_amdgcn_rcpf(1.0f + e);
        float hv = fmaf(-2.0f, rc, 1.0f);                            // tanh(y)
        h[r] = hv;
        qi[r] = __float_as_uint(fmaf(hv, 127.0f, 12582912.0f));      // byte0 = q mod 256
      }
      pend[m] = h;
      unsigned p0 = __builtin_amdgcn_perm(qi[1], qi[0], 0x0c0c0400u);
      unsigned p1 = __builtin_amdgcn_perm(qi[3], qi[2], 0x04000c0cu);
      *(unsigned*)(hb + nxt * 8448 + ldsw + m * 16) = p0 | p1;
    }

    // confirm flag[t+1] (hot path: fv already 1, zero cost)
    if (tid == 0 && fv == 0) {
      while (__hip_atomic_load(&flags[tf * 4 + g], __ATOMIC_ACQUIRE,
                               __HIP_MEMORY_SCOPE_AGENT) == 0)
        __builtin_amdgcn_s_sleep(2);
    }
    __syncthreads();
    xwp += 131072;   // next slab (32768 floats)
  }

  // epilogue: h_seq[T-1] and h_last
#pragma unroll
  for (int m = 0; m < 4; ++m) {
    *(f32x4*)(hsp + m * 16) = pend[m];
    *(f32x4*)(out + (size_t)T_LEN * NBATCH * HSZ +
              (size_t)(g * 16 + lr) * HSZ + j0 + m * 16) = pend[m];
  }
}

extern "C" void kernel_launch(void* const* d_in, const int* in_sizes, int n_in,
                              void* d_out, int out_size, void* d_ws, size_t ws_size,
                              hipStream_t stream) {
  const float* x   = (const float*)d_in[0];
  const float* h0  = (const float*)d_in[1];
  const float* Wih = (const float*)d_in[2];
  const float* Whh = (const float*)d_in[3];
  const float* bih = (const float*)d_in[4];
  const float* bhh = (const float*)d_in[5];
  float* out = (float*)d_out;
  int* flags = (int*)d_ws;   // 2048 ints

  init_flags<<<4, 512, 0, stream>>>(flags);
  rnn_fused<<<4 + NPROJ, 512, 0, stream>>>(x, h0, Wih, Whh, bih, bhh, out, flags);
}

// Round 5
// 1024.011 us; speedup vs baseline: 1.7228x; 1.7228x over previous
//
#include <hip/hip_runtime.h>

// Elman RNN, T=512 B=64 I=256 H=512, fp32 in/out. Two dispatches (R3 struct):
// k1: xw = W_ih x + b_ih + b_hh via bf16 hi/lo MFMA -> d_out in MFMA
//     C-fragment order ((t*4+g)*32+mt)*64+L)*4.  (R1-proven, absmax 0.0039)
// k2: 4 persistent WGs x 8 waves. W_hh int8 register-resident (128 regs ->
//     AGPR side of unified file). h int8 double-buffered LDS (stride 528).
//     R5 changes vs R3: xw loaded same-step (latency hidden by MFMA chain),
//     magic-number quant + v_perm pack epilogue, pointer-increment
//     addressing, explicit B[8] preload after barrier.

#define T_LEN 512
#define NBATCH 64
#define ISZ 256
#define HSZ 512

typedef __attribute__((ext_vector_type(8))) short short8;
typedef __attribute__((ext_vector_type(4))) int int4v;
typedef __attribute__((ext_vector_type(4))) float f32x4;

__device__ __forceinline__ unsigned short f2bf(float f) {
  unsigned u = __float_as_uint(f);
  u += 0x7fffu + ((u >> 16) & 1u);   // RNE
  return (unsigned short)(u >> 16);
}
__device__ __forceinline__ float bf2f(unsigned short h) {
  return __uint_as_float(((unsigned)h) << 16);
}

__device__ __forceinline__ void split_bf(f32x4 a, f32x4 b, short8& hi, short8& lo) {
#pragma unroll
  for (int i = 0; i < 4; ++i) {
    unsigned short h = f2bf(a[i]);
    hi[i] = (short)h;
    lo[i] = (short)f2bf(a[i] - bf2f(h));
    unsigned short h2 = f2bf(b[i]);
    hi[i + 4] = (short)h2;
    lo[i + 4] = (short)f2bf(b[i] - bf2f(h2));
  }
}

// ---------------------------------------------------------------------------
// Kernel 1: input projection (R1-proven).
// ---------------------------------------------------------------------------
__global__ __launch_bounds__(512) void xw_proj(
    const float* __restrict__ x, const float* __restrict__ Wih,
    const float* __restrict__ bih, const float* __restrict__ bhh,
    float* __restrict__ out) {
  __shared__ __align__(16) short xhi[16][264];
  __shared__ __align__(16) short xlo[16][264];

  const int tid = threadIdx.x;
  const int w  = tid >> 6;
  const int L  = tid & 63;
  const int lr = L & 15;
  const int lg = L >> 4;

  const int mhalf = blockIdx.x & 1;
  const int grp   = blockIdx.x >> 1;

  short8 Ahi[2][8], Alo[2][8];
  f32x4 bias[2];
  int mt[2];
#pragma unroll
  for (int m = 0; m < 2; ++m) {
    mt[m] = mhalf * 16 + 2 * w + m;
    int j = mt[m] * 16 + lr;
#pragma unroll
    for (int kt = 0; kt < 8; ++kt) {
      int k = kt * 32 + lg * 8;
      const f32x4 v0 = *(const f32x4*)(Wih + j * ISZ + k);
      const f32x4 v1 = *(const f32x4*)(Wih + j * ISZ + k + 4);
      split_bf(v0, v1, Ahi[m][kt], Alo[m][kt]);
    }
    int j0 = mt[m] * 16 + lg * 4;
    f32x4 b1 = *(const f32x4*)(bih + j0);
    f32x4 b2 = *(const f32x4*)(bhh + j0);
    bias[m] = b1 + b2;
  }

  for (int it = 0; it < 8; ++it) {
    const int tau = grp * 8 + it;
    const int t = tau >> 2;
    const int g = tau & 3;

    __syncthreads();
    {
      const int f   = tid * 8;
      const int row = f >> 8;
      const int i0  = f & 255;
      const float* p = x + ((size_t)(t * NBATCH + g * 16 + row) * ISZ + i0);
      const f32x4 v0 = *(const f32x4*)p;
      const f32x4 v1 = *(const f32x4*)(p + 4);
      short8 hi, lo;
      split_bf(v0, v1, hi, lo);
      *(short8*)(&xhi[row][i0]) = hi;
      *(short8*)(&xlo[row][i0]) = lo;
    }
    __syncthreads();

    f32x4 acc[2];
    acc[0] = f32x4{0.f, 0.f, 0.f, 0.f};
    acc[1] = f32x4{0.f, 0.f, 0.f, 0.f};
#pragma unroll
    for (int kt = 0; kt < 8; ++kt) {
      int koff = kt * 32 + lg * 8;
      short8 bh = *(const short8*)(&xhi[lr][koff]);
      short8 bl = *(const short8*)(&xlo[lr][koff]);
      acc[0] = __builtin_amdgcn_mfma_f32_16x16x32_bf16(Ahi[0][kt], bh, acc[0], 0, 0, 0);
      acc[1] = __builtin_amdgcn_mfma_f32_16x16x32_bf16(Ahi[1][kt], bh, acc[1], 0, 0, 0);
      acc[0] = __builtin_amdgcn_mfma_f32_16x16x32_bf16(Alo[0][kt], bh, acc[0], 0, 0, 0);
      acc[1] = __builtin_amdgcn_mfma_f32_16x16x32_bf16(Alo[1][kt], bh, acc[1], 0, 0, 0);
      acc[0] = __builtin_amdgcn_mfma_f32_16x16x32_bf16(Ahi[0][kt], bl, acc[0], 0, 0, 0);
      acc[1] = __builtin_amdgcn_mfma_f32_16x16x32_bf16(Ahi[1][kt], bl, acc[1], 0, 0, 0);
    }
#pragma unroll
    for (int m = 0; m < 2; ++m) {
      f32x4 r = acc[m] + bias[m];
      *(f32x4*)(out + (size_t)((((t * 4 + g) * 32 + mt[m]) * 64) + L) * 4) = r;
    }
  }
}

// ---------------------------------------------------------------------------
// Kernel 2: recurrence. 4 blocks x 512 threads (8 waves, 2/SIMD).
// ---------------------------------------------------------------------------
__global__ __launch_bounds__(512, 2) void rnn_scan_i8(
    const float* __restrict__ Whh, const float* __restrict__ h0,
    float* __restrict__ out) {
  __shared__ __align__(16) char hb[2 * 16 * 528];

  const int tid = threadIdx.x;
  const int w  = tid >> 6;    // 0..7
  const int L  = tid & 63;
  const int lr = L & 15;
  const int lg = L >> 4;
  const int g  = blockIdx.x;

  const float QS  = 127.0f * 22.627416997969522f;                 // 127*sqrt(512)
  const float DEQ = (float)(1.0 / (127.0 * 127.0 * 22.627416997969522));

  // ---- quantize W_hh: 4 m-tiles x 8 k-tiles x int4v = 128 regs/lane
  int4v A[4][8];
#pragma unroll
  for (int m = 0; m < 4; ++m) {
    const int j = (4 * w + m) * 16 + lr;         // A-row (m = lane&15)
#pragma unroll
    for (int kt = 0; kt < 8; ++kt) {
      const float* p = Whh + (size_t)j * HSZ + kt * 64 + lg * 16;  // k=quad*16+i
      int dw[4];
#pragma unroll
      for (int d = 0; d < 4; ++d) {
        f32x4 v = *(const f32x4*)(p + d * 4);
        int pk = 0;
#pragma unroll
        for (int i = 0; i < 4; ++i) {
          float q = __builtin_rintf(fminf(fmaxf(v[i] * QS, -127.f), 127.f));
          pk |= ((int)q & 255) << (8 * i);
        }
        dw[d] = pk;
      }
      A[m][kt] = int4v{dw[0], dw[1], dw[2], dw[3]};
    }
  }

  // ---- stage h0 as int8 into buffer 0: 16 rows x 512
  {
    const int row = tid >> 5;           // 0..15
    const int k0  = (tid & 31) * 16;    // 0..496
    const float* p = h0 + ((size_t)(g * 16 + row) * HSZ + k0);
    int dw[4];
#pragma unroll
    for (int c = 0; c < 4; ++c) {
      f32x4 v = *(const f32x4*)(p + c * 4);
      int pk = 0;
#pragma unroll
      for (int i = 0; i < 4; ++i) {
        float q = __builtin_rintf(fminf(fmaxf(v[i] * 127.f, -127.f), 127.f));
        pk |= ((int)q & 255) << (8 * i);
      }
      dw[c] = pk;
    }
    *(int4v*)(&hb[row * 528 + k0]) = int4v{dw[0], dw[1], dw[2], dw[3]};
  }
  __syncthreads();

  const int j0 = 4 * w * 16 + lg * 4;                    // column base (floats)
  const char* xwp = (const char*)out + ((size_t)(g * 32 + 4 * w) * 64 + L) * 16;
  float* hsp = out + (size_t)(g * 16 + lr) * HSZ + j0;   // slab-0 h_seq base
  const int ldsr = lr * 528 + lg * 16;
  const int ldsw = lr * 528 + j0;

  f32x4 pend[4];

  for (int t = 0; t < T_LEN; ++t) {
    const int cur = t & 1, nxt = cur ^ 1;
    const int cb = cur * 8448, nb = nxt * 8448;

    // xw[t]: plain cached loads, issued now, consumed in epilogue ~1.5k cyc later
    f32x4 xw[4];
#pragma unroll
    for (int m = 0; m < 4; ++m) xw[m] = *(const f32x4*)(xwp + m * 1024);

    // deferred h_seq store for slab t-1 (readers drained at t-1's barrier)
    if (t > 0) {
#pragma unroll
      for (int m = 0; m < 4; ++m) *(f32x4*)(hsp + m * 16) = pend[m];
      hsp += NBATCH * HSZ;
    }

    // B preload: 8 b128 in flight, then 32 MFMAs (4 independent acc chains)
    int4v B[8];
#pragma unroll
    for (int kt = 0; kt < 8; ++kt)
      B[kt] = *(const int4v*)(&hb[cb + ldsr + kt * 64]);

    int4v acc[4];
#pragma unroll
    for (int m = 0; m < 4; ++m) acc[m] = int4v{0, 0, 0, 0};
#pragma unroll
    for (int kt = 0; kt < 8; ++kt)
#pragma unroll
      for (int m = 0; m < 4; ++m)
        acc[m] = __builtin_amdgcn_mfma_i32_16x16x64_i8(A[m][kt], B[kt], acc[m], 0, 0, 0);

    // epilogue: dequant + tanh + magic quant + v_perm pack (R4-proven numerics)
#pragma unroll
    for (int m = 0; m < 4; ++m) {
      unsigned qi[4];
      f32x4 h;
#pragma unroll
      for (int r = 0; r < 4; ++r) {
        float y  = fmaf((float)acc[m][r], DEQ, xw[m][r]);
        float e  = __builtin_amdgcn_exp2f(y * 2.8853900817779268f);  // e^{2y}
        float rc = __builtin_amdgcn_rcpf(1.0f + e);
        float hv = fmaf(-2.0f, rc, 1.0f);                            // tanh(y)
        h[r] = hv;
        qi[r] = __float_as_uint(fmaf(hv, 127.0f, 12582912.0f));      // b0 = q mod 256
      }
      pend[m] = h;
      unsigned p0 = __builtin_amdgcn_perm(qi[1], qi[0], 0x0c0c0400u); // [0,0,q1,q0]
      unsigned p1 = __builtin_amdgcn_perm(qi[3], qi[2], 0x04000c0cu); // [q3,q2,0,0]
      *(unsigned*)(&hb[nb + ldsw + m * 16]) = p0 | p1;
    }

    __syncthreads();
    xwp += 131072;   // next (t, g) slab
  }

  // epilogue: h_seq[T-1] and h_last
#pragma unroll
  for (int m = 0; m < 4; ++m) {
    *(f32x4*)(hsp + m * 16) = pend[m];
    *(f32x4*)(out + (size_t)T_LEN * NBATCH * HSZ +
              (size_t)(g * 16 + lr) * HSZ + j0 + m * 16) = pend[m];
  }
}

extern "C" void kernel_launch(void* const* d_in, const int* in_sizes, int n_in,
                              void* d_out, int out_size, void* d_ws, size_t ws_size,
                              hipStream_t stream) {
  const float* x   = (const float*)d_in[0];
  const float* h0  = (const float*)d_in[1];
  const float* Wih = (const float*)d_in[2];
  const float* Whh = (const float*)d_in[3];
  const float* bih = (const float*)d_in[4];
  const float* bhh = (const float*)d_in[5];
  float* out = (float*)d_out;

  xw_proj<<<512, 512, 0, stream>>>(x, Wih, bih, bhh, out);
  rnn_scan_i8<<<4, 512, 0, stream>>>(Whh, h0, out);
}